// Round 4
// baseline (1049.983 us; speedup 1.0000x reference)
//
#include <hip/hip_runtime.h>
#include <hip/hip_fp16.h>

#define Tt 512

typedef _Float16 f16x8 __attribute__((ext_vector_type(8)));
typedef float    f32x4 __attribute__((ext_vector_type(4)));
typedef _Float16 h2vec __attribute__((ext_vector_type(2)));

// Workspace byte offsets
#define BP16_OFF 0ul                              // fp16 B panel [1280][320]
#define BP16_BYTES (2ul*1280*320)                 // 819,200
#define WHH2_OFF (BP16_OFF + BP16_BYTES)
#define WHH2_BYTES (4ul*2*4*19*640)               // 389,120 (uint-packed half2, gate-major)
#define BIAS_OFF (WHH2_OFF + WHH2_BYTES)
#define BIAS_BYTES (4ul*1280)
#define XG_OFF   (4ul*1024*1024)                  // fp16 xg [65536][1280] = 167.8 MB

__device__ __forceinline__ float fdot2(unsigned a, unsigned b, float c) {
#if __has_builtin(__builtin_amdgcn_fdot2)
    return __builtin_amdgcn_fdot2(__builtin_bit_cast(h2vec, a),
                                  __builtin_bit_cast(h2vec, b), c, false);
#else
    __half2 ha = __builtin_bit_cast(__half2, a);
    __half2 hb = __builtin_bit_cast(__half2, b);
    return c + __half2float(ha.x) * __half2float(hb.x)
             + __half2float(ha.y) * __half2float(hb.y);
#endif
}

__device__ __forceinline__ float tanh_fast(float v) {
    float av = fminf(fabsf(v), 15.f);
    float e  = __expf(2.f * av);
    float r  = (e - 1.f) / (e + 1.f);
    return copysignf(r, v);
}
__device__ __forceinline__ float sigmoid_fast(float v) {
    return 1.f / (1.f + __expf(-v));
}

// ---------------- Kernel 0: pack weights ----------------
// Bp[n][k] fp16 for the GEMM (n = dir*640+j, k = e padded to 320).
// Whh2: uint(half2) at ((dir*4+q)*19 + kk4)*640 + u*4 + c
//   = half2( W_hh[q*150+u][2*(kk4*4+c)], W_hh[q*150+u][2*(kk4*4+c)+1] )
//   k padded to 152 (19 uint4-chunks of 8 halfs), u padded to 160, zeros in pads.
__global__ void pack_weights(const float* __restrict__ Wih_f, const float* __restrict__ Whh_f,
                             const float* __restrict__ b_f,
                             const float* __restrict__ Wih_b, const float* __restrict__ Whh_b,
                             const float* __restrict__ b_b,
                             __half* __restrict__ Bp, unsigned* __restrict__ Whh2,
                             float* __restrict__ bias_p) {
    int idx = blockIdx.x * 256 + threadIdx.x;
    const int T1 = 1280 * 320;        // 409600
    const int T2 = 2 * 4 * 19 * 640;  // 97280
    const int T3 = 1280;
    if (idx < T1) {
        int n = idx / 320, k = idx % 320;
        int dir = (n >= 640), j = n - dir * 640;
        const float* W = dir ? Wih_b : Wih_f;
        Bp[idx] = __float2half((j < 600 && k < 300) ? W[j * 300 + k] : 0.f);
    } else if ((idx -= T1) < T2) {
        int dir  = idx / 48640;
        int rem  = idx % 48640;
        int q    = rem / 12160;
        int rem2 = rem % 12160;
        int kk4  = rem2 / 640;
        int r3   = rem2 % 640;
        int u = r3 >> 2, c = r3 & 3;
        int k0 = (kk4 * 4 + c) * 2;
        const float* W = dir ? Whh_b : Whh_f;
        int row = q * 150 + u;
        float lo = (u < 150 && k0     < 150) ? W[row * 150 + k0]     : 0.f;
        float hi = (u < 150 && k0 + 1 < 150) ? W[row * 150 + k0 + 1] : 0.f;
        union { __half h[2]; unsigned x; } pk;
        pk.h[0] = __float2half(lo);
        pk.h[1] = __float2half(hi);
        Whh2[idx] = pk.x;
    } else if ((idx -= T2) < T3) {
        int n = idx;
        int dir = (n >= 640), j = n - dir * 640;
        const float* bb = dir ? b_b : b_f;
        bias_p[n] = (j < 600) ? bb[j] : 0.f;
    }
}

// ---------------- Kernel 1: xg GEMM via MFMA (unchanged from R3) ----------------
__global__ __launch_bounds__(256) void gemm_xg(const float* __restrict__ x,
                                               const uint4* __restrict__ Bp,
                                               const float* __restrict__ bias_p,
                                               __half* __restrict__ xg) {
    __shared__ uint4 Bsh[5120];
    const int tid = threadIdx.x;
    const int bid = blockIdx.x;
    const int xcd = bid & 7, li = bid >> 3;
    const int mb  = xcd * 64 + li / 10;
    const int nb  = li % 10;

    {
        const uint4* src = Bp + (size_t)nb * 128 * 40;
        for (int c = tid; c < 5120; c += 256) {
            int n = c / 40, ch = c - n * 40;
            Bsh[n * 40 + (ch ^ (n & 7))] = src[c];
        }
    }

    const int w  = tid >> 6;
    const int l  = tid & 63;
    const int wr = w >> 1, wc = w & 1;
    const int lr = l & 15, kg = l >> 4;

    f32x4 acc[4][4];
#pragma unroll
    for (int mf = 0; mf < 4; ++mf)
#pragma unroll
        for (int nf = 0; nf < 4; ++nf) acc[mf][nf] = (f32x4)0.f;

    const float* arow0 = x + (size_t)(mb * 128 + wr * 64 + lr) * 300 + kg * 8;
    const float* arow1 = arow0 + 16 * 300;
    const float* arow2 = arow0 + 32 * 300;
    const float* arow3 = arow0 + 48 * 300;
    const float4 fz4 = make_float4(0.f, 0.f, 0.f, 0.f);

    float cur[2][4][8];
#define LOADA(BUF, KB, GUARD)                                                   \
    {                                                                           \
        const float* ap_[4] = {arow0, arow1, arow2, arow3};                     \
        _Pragma("unroll")                                                       \
        for (int mf = 0; mf < 4; ++mf) {                                        \
            const float* ap = ap_[mf] + (KB) * 32;                              \
            *(float4*)&cur[BUF][mf][0] =                                        \
                (!(GUARD) || (KB) * 32 + kg * 8 < 300) ? *(const float4*)ap : fz4; \
            *(float4*)&cur[BUF][mf][4] =                                        \
                (!(GUARD) || (KB) * 32 + kg * 8 + 4 < 300) ? *(const float4*)(ap + 4) : fz4; \
        }                                                                       \
    }

    __syncthreads();

    LOADA(0, 0, false);
#pragma unroll
    for (int kb = 0; kb < 10; ++kb) {
        const int pb = kb & 1, nx = pb ^ 1;
        if (kb < 8)       { LOADA(nx, kb + 1, false); }
        else if (kb == 8) { LOADA(nx, 9, true); }

        uint4 bf[4];
#pragma unroll
        for (int nf = 0; nf < 4; ++nf)
            bf[nf] = Bsh[(wc * 64 + nf * 16 + lr) * 40 + ((kb * 4 + kg) ^ (lr & 7))];

        f16x8 af[4];
#pragma unroll
        for (int mf = 0; mf < 4; ++mf)
#pragma unroll
            for (int i = 0; i < 8; ++i) af[mf][i] = (_Float16)cur[pb][mf][i];

#pragma unroll
        for (int mf = 0; mf < 4; ++mf)
#pragma unroll
            for (int nf = 0; nf < 4; ++nf)
                acc[mf][nf] = __builtin_amdgcn_mfma_f32_16x16x32_f16(
                    __builtin_bit_cast(f16x8, bf[nf]), af[mf], acc[mf][nf], 0, 0, 0);
    }

    const int mrow = mb * 128 + wr * 64;
    const int ncol = nb * 128 + wc * 64;
#pragma unroll
    for (int mf = 0; mf < 4; ++mf) {
        int m_g = mrow + mf * 16 + lr;
        __half* orow = xg + (size_t)m_g * 1280;
#pragma unroll
        for (int nf = 0; nf < 4; ++nf) {
            int n_g = ncol + nf * 16 + kg * 4;
            float4 bv = *(const float4*)(bias_p + n_g);
            f32x4 v = acc[mf][nf];
            union { __half h[4]; uint2 u; } pk;
            pk.h[0] = __float2half(v[0] + bv.x);
            pk.h[1] = __float2half(v[1] + bv.y);
            pk.h[2] = __float2half(v[2] + bv.z);
            pk.h[3] = __float2half(v[3] + bv.w);
            *(uint2*)(orow + n_g) = pk.u;
        }
    }
#undef LOADA
}

// ---------------- Kernel 2: recurrence + pooling ----------------
// 256 blocks (dir, sample) x 192 threads (3 waves). Thread u < 150 owns unit u:
// all 4 gates in-register (W_hh: 4x19 uint4 = 304 VGPRs of packed fp16),
// activations in-register, h published to double-buffered LDS, 1 barrier/step.
__global__ __launch_bounds__(192, 1) void lstm_rec(const uint4* __restrict__ Whh4,
                                                   const __half* __restrict__ xg,
                                                   const int* __restrict__ lens,
                                                   float* __restrict__ out) {
    __shared__ unsigned h2[2][76];   // 2 x 152 packed fp16 h (150 used, pad 0)
    const int tid = threadIdx.x;
    const int dir = blockIdx.x & 1;
    const int b   = blockIdx.x >> 1;

    if (tid < 152) ((unsigned*)h2)[tid] = 0u;

    uint4 w4[4][19];
    float xcur[4];
    float c_s = 0.f, hsum = 0.f, hlast = 0.f;
    int Lv = 1, markLast = -1;
    const __half* xbase = xg + (size_t)b * 512 * 1280 + dir * 640 + tid;

    if (tid < 150) {
        const uint4* wsrc = Whh4 + (size_t)dir * (4 * 19 * 160) + tid;
#pragma unroll
        for (int q = 0; q < 4; ++q)
#pragma unroll
            for (int r = 0; r < 19; ++r) w4[q][r] = wsrc[(q * 19 + r) * 160];
        Lv = lens[b];
        markLast = dir ? (Tt - Lv) : (Lv - 1);
        int t0 = dir ? 511 : 0;
#pragma unroll
        for (int q = 0; q < 4; ++q)
            xcur[q] = __half2float(xbase[(size_t)t0 * 1280 + q * 150]);
    }
    __syncthreads();

    for (int step = 0; step < Tt; ++step) {
        const int rbuf = step & 1;
        __half xn[4];
        if (tid < 150) {
            int sp = (step + 1 < Tt) ? step + 1 : (Tt - 1);
            int tn = dir ? (511 - sp) : sp;
#pragma unroll
            for (int q = 0; q < 4; ++q)
                xn[q] = xbase[(size_t)tn * 1280 + q * 150];   // prefetch next step

            float a0 = xcur[0], a1 = xcur[1], a2 = xcur[2], a3 = xcur[3];
            const uint4* h4r = (const uint4*)&h2[rbuf][0];
#pragma unroll
            for (int r = 0; r < 19; ++r) {
                uint4 hv = h4r[r];                 // LDS broadcast
                a0 = fdot2(hv.x, w4[0][r].x, a0);
                a1 = fdot2(hv.x, w4[1][r].x, a1);
                a2 = fdot2(hv.x, w4[2][r].x, a2);
                a3 = fdot2(hv.x, w4[3][r].x, a3);
                a0 = fdot2(hv.y, w4[0][r].y, a0);
                a1 = fdot2(hv.y, w4[1][r].y, a1);
                a2 = fdot2(hv.y, w4[2][r].y, a2);
                a3 = fdot2(hv.y, w4[3][r].y, a3);
                a0 = fdot2(hv.z, w4[0][r].z, a0);
                a1 = fdot2(hv.z, w4[1][r].z, a1);
                a2 = fdot2(hv.z, w4[2][r].z, a2);
                a3 = fdot2(hv.z, w4[3][r].z, a3);
                a0 = fdot2(hv.w, w4[0][r].w, a0);
                a1 = fdot2(hv.w, w4[1][r].w, a1);
                a2 = fdot2(hv.w, w4[2][r].w, a2);
                a3 = fdot2(hv.w, w4[3][r].w, a3);
            }

            float i_ = sigmoid_fast(a0);
            float f_ = sigmoid_fast(a1);
            float g_ = tanh_fast(a2);
            float o_ = sigmoid_fast(a3);
            c_s = f_ * c_s + i_ * g_;
            float h = o_ * tanh_fast(c_s);
            bool in = dir ? (step >= markLast) : (step < Lv);
            if (in) hsum += h;
            if (step == markLast) hlast = h;
            ((__half*)&h2[rbuf ^ 1][0])[tid] = __float2half(h);
#pragma unroll
            for (int q = 0; q < 4; ++q) xcur[q] = __half2float(xn[q]);
        }
        __syncthreads();
    }

    if (tid < 150) {
        out[b * 600 + dir * 150 + tid]       = tanh_fast(hsum / (float)Lv);
        out[b * 600 + 300 + dir * 150 + tid] = tanh_fast(hlast);
    }
}

// ---------------- launch ----------------
extern "C" void kernel_launch(void* const* d_in, const int* in_sizes, int n_in,
                              void* d_out, int out_size, void* d_ws, size_t ws_size,
                              hipStream_t stream) {
    const float* x     = (const float*)d_in[0];
    const int*   lens  = (const int*)d_in[1];
    const float* Wih_f = (const float*)d_in[2];
    const float* Whh_f = (const float*)d_in[3];
    const float* b_f   = (const float*)d_in[4];
    const float* Wih_b = (const float*)d_in[5];
    const float* Whh_b = (const float*)d_in[6];
    const float* b_b   = (const float*)d_in[7];
    float* out = (float*)d_out;
    char*  ws  = (char*)d_ws;

    __half*   Bp     = (__half*)(ws + BP16_OFF);
    unsigned* Whh2   = (unsigned*)(ws + WHH2_OFF);
    float*    bias_p = (float*)(ws + BIAS_OFF);
    __half*   xg     = (__half*)(ws + XG_OFF);

    {
        int total = 1280 * 320 + 2 * 4 * 19 * 640 + 1280;
        int blocks = (total + 255) / 256;
        pack_weights<<<blocks, 256, 0, stream>>>(Wih_f, Whh_f, b_f, Wih_b, Whh_b, b_b,
                                                 Bp, Whh2, bias_p);
    }
    {
        gemm_xg<<<5120, 256, 0, stream>>>(x, (const uint4*)Bp, bias_p, xg);
    }
    {
        lstm_rec<<<256, 192, 0, stream>>>((const uint4*)Whh2, xg, lens, out);
    }
}

// Round 5
// 712.587 us; speedup vs baseline: 1.4735x; 1.4735x over previous
//
#include <hip/hip_runtime.h>
#include <hip/hip_fp16.h>

#define Tt 512

typedef _Float16 f16x8 __attribute__((ext_vector_type(8)));
typedef float    f32x4 __attribute__((ext_vector_type(4)));
typedef _Float16 h2vec __attribute__((ext_vector_type(2)));

// Workspace byte offsets
#define BP16_OFF 0ul                              // fp16 B panel [1280][320]
#define BP16_BYTES (2ul*1280*320)                 // 819,200
#define WHH2_OFF (BP16_OFF + BP16_BYTES)
#define WHH2_BYTES (4ul*2*20*640*4)               // 409,600 (uint-packed half2)
#define BIAS_OFF (WHH2_OFF + WHH2_BYTES)
#define BIAS_BYTES (4ul*1280)
#define XG_OFF   (4ul*1024*1024)                  // fp16 xg [65536][1280] = 167.8 MB

__device__ __forceinline__ float fdot2(unsigned a, unsigned b, float c) {
#if __has_builtin(__builtin_amdgcn_fdot2)
    return __builtin_amdgcn_fdot2(__builtin_bit_cast(h2vec, a),
                                  __builtin_bit_cast(h2vec, b), c, false);
#else
    __half2 ha = __builtin_bit_cast(__half2, a);
    __half2 hb = __builtin_bit_cast(__half2, b);
    return c + __half2float(ha.x) * __half2float(hb.x)
             + __half2float(ha.y) * __half2float(hb.y);
#endif
}

__device__ __forceinline__ float tanh_fast(float v) {
    float av = fminf(fabsf(v), 15.f);
    float e  = __expf(2.f * av);
    float r  = (e - 1.f) / (e + 1.f);
    return copysignf(r, v);
}
__device__ __forceinline__ float sigmoid_fast(float v) {
    return 1.f / (1.f + __expf(-v));
}

// ---------------- Kernel 0: pack weights ----------------
// Bp[n][k] fp16: n = dir*640+j, k = e padded to 320.
// Whh2[((dir*20 + r)*640 + j)*4 + c] = half2(W_hh[j][8r+2c], W_hh[j][8r+2c+1])
__global__ void pack_weights(const float* __restrict__ Wih_f, const float* __restrict__ Whh_f,
                             const float* __restrict__ b_f,
                             const float* __restrict__ Wih_b, const float* __restrict__ Whh_b,
                             const float* __restrict__ b_b,
                             __half* __restrict__ Bp, unsigned* __restrict__ Whh2,
                             float* __restrict__ bias_p) {
    int idx = blockIdx.x * 256 + threadIdx.x;
    const int T1 = 1280 * 320;
    const int T2 = 2 * 20 * 640 * 4;
    const int T3 = 1280;
    if (idx < T1) {
        int n = idx / 320, k = idx % 320;
        int dir = (n >= 640), j = n - dir * 640;
        const float* W = dir ? Wih_b : Wih_f;
        Bp[idx] = __float2half((j < 600 && k < 300) ? W[j * 300 + k] : 0.f);
    } else if ((idx -= T1) < T2) {
        int dir  = idx / 51200;
        int rem  = idx % 51200;
        int r    = rem / 2560;
        int rem2 = rem % 2560;
        int j = rem2 >> 2, c = rem2 & 3;
        int k = r * 8 + c * 2;
        const float* W = dir ? Whh_b : Whh_f;
        float lo = (j < 600 && k     < 150) ? W[j * 150 + k]     : 0.f;
        float hi = (j < 600 && k + 1 < 150) ? W[j * 150 + k + 1] : 0.f;
        union { __half h[2]; unsigned u; } pk;
        pk.h[0] = __float2half(lo);
        pk.h[1] = __float2half(hi);
        Whh2[idx] = pk.u;
    } else if ((idx -= T2) < T3) {
        int n = idx;
        int dir = (n >= 640), j = n - dir * 640;
        const float* bb = dir ? b_b : b_f;
        bias_p[n] = (j < 600) ? bb[j] : 0.f;
    }
}

// ---------------- Kernel 1: xg GEMM via MFMA (unchanged from R3) ----------------
__global__ __launch_bounds__(256) void gemm_xg(const float* __restrict__ x,
                                               const uint4* __restrict__ Bp,
                                               const float* __restrict__ bias_p,
                                               __half* __restrict__ xg) {
    __shared__ uint4 Bsh[5120];
    const int tid = threadIdx.x;
    const int bid = blockIdx.x;
    const int xcd = bid & 7, li = bid >> 3;
    const int mb  = xcd * 64 + li / 10;
    const int nb  = li % 10;

    {
        const uint4* src = Bp + (size_t)nb * 128 * 40;
        for (int c = tid; c < 5120; c += 256) {
            int n = c / 40, ch = c - n * 40;
            Bsh[n * 40 + (ch ^ (n & 7))] = src[c];
        }
    }

    const int w  = tid >> 6;
    const int l  = tid & 63;
    const int wr = w >> 1, wc = w & 1;
    const int lr = l & 15, kg = l >> 4;

    f32x4 acc[4][4];
#pragma unroll
    for (int mf = 0; mf < 4; ++mf)
#pragma unroll
        for (int nf = 0; nf < 4; ++nf) acc[mf][nf] = (f32x4)0.f;

    const float* arow0 = x + (size_t)(mb * 128 + wr * 64 + lr) * 300 + kg * 8;
    const float* arow1 = arow0 + 16 * 300;
    const float* arow2 = arow0 + 32 * 300;
    const float* arow3 = arow0 + 48 * 300;
    const float4 fz4 = make_float4(0.f, 0.f, 0.f, 0.f);

    float cur[2][4][8];
#define LOADA(BUF, KB, GUARD)                                                   \
    {                                                                           \
        const float* ap_[4] = {arow0, arow1, arow2, arow3};                     \
        _Pragma("unroll")                                                       \
        for (int mf = 0; mf < 4; ++mf) {                                        \
            const float* ap = ap_[mf] + (KB) * 32;                              \
            *(float4*)&cur[BUF][mf][0] =                                        \
                (!(GUARD) || (KB) * 32 + kg * 8 < 300) ? *(const float4*)ap : fz4; \
            *(float4*)&cur[BUF][mf][4] =                                        \
                (!(GUARD) || (KB) * 32 + kg * 8 + 4 < 300) ? *(const float4*)(ap + 4) : fz4; \
        }                                                                       \
    }

    __syncthreads();

    LOADA(0, 0, false);
#pragma unroll
    for (int kb = 0; kb < 10; ++kb) {
        const int pb = kb & 1, nx = pb ^ 1;
        if (kb < 8)       { LOADA(nx, kb + 1, false); }
        else if (kb == 8) { LOADA(nx, 9, true); }

        uint4 bf[4];
#pragma unroll
        for (int nf = 0; nf < 4; ++nf)
            bf[nf] = Bsh[(wc * 64 + nf * 16 + lr) * 40 + ((kb * 4 + kg) ^ (lr & 7))];

        f16x8 af[4];
#pragma unroll
        for (int mf = 0; mf < 4; ++mf)
#pragma unroll
            for (int i = 0; i < 8; ++i) af[mf][i] = (_Float16)cur[pb][mf][i];

#pragma unroll
        for (int mf = 0; mf < 4; ++mf)
#pragma unroll
            for (int nf = 0; nf < 4; ++nf)
                acc[mf][nf] = __builtin_amdgcn_mfma_f32_16x16x32_f16(
                    __builtin_bit_cast(f16x8, bf[nf]), af[mf], acc[mf][nf], 0, 0, 0);
    }

    const int mrow = mb * 128 + wr * 64;
    const int ncol = nb * 128 + wc * 64;
#pragma unroll
    for (int mf = 0; mf < 4; ++mf) {
        int m_g = mrow + mf * 16 + lr;
        __half* orow = xg + (size_t)m_g * 1280;
#pragma unroll
        for (int nf = 0; nf < 4; ++nf) {
            int n_g = ncol + nf * 16 + kg * 4;
            float4 bv = *(const float4*)(bias_p + n_g);
            f32x4 v = acc[mf][nf];
            union { __half h[4]; uint2 u; } pk;
            pk.h[0] = __float2half(v[0] + bv.x);
            pk.h[1] = __float2half(v[1] + bv.y);
            pk.h[2] = __float2half(v[2] + bv.z);
            pk.h[3] = __float2half(v[3] + bv.w);
            *(uint2*)(orow + n_g) = pk.u;
        }
    }
#undef LOADA
}

// ---------------- Kernel 2: recurrence + pooling ----------------
// 256 blocks (dir, sample) x 640 threads. Thread j owns gate column j; its
// 150 W_hh weights are PINNED in 20 uint4 VGPRs via asm (anti-rematerialize).
// Each gate-thread applies its own activation before the gl[] exchange.
__global__ __launch_bounds__(640, 1) void lstm_rec(const uint4* __restrict__ Whh2,
                                                   const __half* __restrict__ xg,
                                                   const int* __restrict__ lens,
                                                   float* __restrict__ out) {
    __shared__ unsigned h2[80];
    __shared__ float gl[640];
    const int tid = threadIdx.x;
    const int dir = blockIdx.x & 1;
    const int b   = blockIdx.x >> 1;
    const int gtype = tid / 150;     // 0=i 1=f 2=g 3=o (4 = pad threads)

    uint4 w[20];
    const uint4* wsrc = Whh2 + dir * (20 * 640) + tid;
#pragma unroll
    for (int r = 0; r < 20; ++r) w[r] = wsrc[r * 640];
    // Pin: allocator cannot rematerialize asm outputs -> weights stay in VGPRs.
#pragma unroll
    for (int r = 0; r < 20; ++r)
        asm volatile("" : "+v"(w[r].x), "+v"(w[r].y), "+v"(w[r].z), "+v"(w[r].w));

    if (tid < 80) h2[tid] = 0u;

    float c_s = 0.f, hsum = 0.f, hlast = 0.f;
    int Lv = 1, markLast = -1;
    if (tid < 150) {
        Lv = lens[b];
        markLast = dir ? (Tt - Lv) : (Lv - 1);
    }

    const __half* xbase = xg + (size_t)b * 512 * 1280 + dir * 640 + tid;
    __syncthreads();

    int t0 = dir ? 511 : 0;
    float xv = __half2float(xbase[(size_t)t0 * 1280]);
    const uint4* h4 = (const uint4*)h2;
    for (int step = 0; step < Tt; ++step) {
        int sp = (step + 1 < Tt) ? step + 1 : (Tt - 1);
        int tn = dir ? (511 - sp) : sp;
        __half xn = xbase[(size_t)tn * 1280];   // prefetch next step

        float a0 = xv, a1 = 0.f, a2 = 0.f, a3 = 0.f;
#pragma unroll
        for (int r = 0; r < 20; ++r) {
            uint4 hv = h4[r];                   // LDS broadcast
            a0 = fdot2(hv.x, w[r].x, a0);
            a1 = fdot2(hv.y, w[r].y, a1);
            a2 = fdot2(hv.z, w[r].z, a2);
            a3 = fdot2(hv.w, w[r].w, a3);
        }
        float a = (a0 + a1) + (a2 + a3);
        // act1: every thread activates its own gate (tanh(x) = 2*sigmoid(2x)-1)
        float xx = (gtype == 2) ? 2.f * a : a;
        float s  = sigmoid_fast(xx);
        gl[tid]  = (gtype == 2) ? 2.f * s - 1.f : s;
        __syncthreads();

        if (tid < 150) {
            float i_ = gl[tid];
            float f_ = gl[150 + tid];
            float g_ = gl[300 + tid];
            float o_ = gl[450 + tid];
            c_s = f_ * c_s + i_ * g_;
            float h = o_ * tanh_fast(c_s);
            bool in = dir ? (step >= markLast) : (step < Lv);
            if (in) hsum += h;
            if (step == markLast) hlast = h;
            ((__half*)h2)[tid] = __float2half(h);
        }
        __syncthreads();
        xv = __half2float(xn);
    }

    if (tid < 150) {
        out[b * 600 + dir * 150 + tid]       = tanh_fast(hsum / (float)Lv);
        out[b * 600 + 300 + dir * 150 + tid] = tanh_fast(hlast);
    }
}

// ---------------- launch ----------------
extern "C" void kernel_launch(void* const* d_in, const int* in_sizes, int n_in,
                              void* d_out, int out_size, void* d_ws, size_t ws_size,
                              hipStream_t stream) {
    const float* x     = (const float*)d_in[0];
    const int*   lens  = (const int*)d_in[1];
    const float* Wih_f = (const float*)d_in[2];
    const float* Whh_f = (const float*)d_in[3];
    const float* b_f   = (const float*)d_in[4];
    const float* Wih_b = (const float*)d_in[5];
    const float* Whh_b = (const float*)d_in[6];
    const float* b_b   = (const float*)d_in[7];
    float* out = (float*)d_out;
    char*  ws  = (char*)d_ws;

    __half*   Bp     = (__half*)(ws + BP16_OFF);
    unsigned* Whh2   = (unsigned*)(ws + WHH2_OFF);
    float*    bias_p = (float*)(ws + BIAS_OFF);
    __half*   xg     = (__half*)(ws + XG_OFF);

    {
        int total = 1280 * 320 + 2 * 20 * 640 * 4 + 1280;
        int blocks = (total + 255) / 256;
        pack_weights<<<blocks, 256, 0, stream>>>(Wih_f, Whh_f, b_f, Wih_b, Whh_b, b_b,
                                                 Bp, Whh2, bias_p);
    }
    {
        gemm_xg<<<5120, 256, 0, stream>>>(x, (const uint4*)Bp, bias_p, xg);
    }
    {
        lstm_rec<<<256, 640, 0, stream>>>((const uint4*)Whh2, xg, lens, out);
    }
}